// Round 5
// baseline (132.883 us; speedup 1.0000x reference)
//
#include <hip/hip_runtime.h>
#include <hip/hip_bf16.h>

#define N 8192
#define D 256
#define NSLICE 16
#define BM 128                       // rows per block (4 waves x 32 rows)
#define CB 32                        // cols per staged LDS tile
#define COLS_PER_SLICE (N / NSLICE)  // 512
#define NT (COLS_PER_SLICE / CB)     // 16 tiles per block
#define NRB (N / BM)                 // 64 row blocks

#define CSHIFT 160.0f                // fixed base-2 LSE shift
#define K2LOG2E 2.885390082f         // (1/T) * log2(e) = 2 * 1.44269504
#define LN2F 0.6931471805599453f

typedef __attribute__((ext_vector_type(8))) short bf16x8;
typedef __attribute__((ext_vector_type(4))) float f32x4;

__device__ inline float fast_exp2(float x) { return __builtin_amdgcn_exp2f(x); }
__device__ inline float fast_log2(float x) { return __builtin_amdgcn_logf(x); }

// async global->LDS, 16B per lane; LDS dest = wave-uniform base + lane*16,
// global src is per-lane (carries the fragment layout).
__device__ inline void gload_lds16(const ushort* g, ushort* l) {
    __builtin_amdgcn_global_load_lds(
        (const __attribute__((address_space(1))) void*)g,
        (__attribute__((address_space(3))) void*)l, 16, 0, 0);
}

__device__ inline ushort f2bf(float x) {
    __hip_bfloat16 h = __float2bfloat16(x);
    return *reinterpret_cast<ushort*>(&h);
}

// ---------------- kernel 0: fp32 -> bf16 conversion ----------------
__global__ void convert_bf16(const float* __restrict__ F, const float* __restrict__ Imp,
                             ushort* __restrict__ Fb, ushort* __restrict__ Ib) {
    const int i = blockIdx.x * blockDim.x + threadIdx.x;  // float4 index
    const int total4 = N * D / 4;
    const float4* src = (blockIdx.y == 0) ? (const float4*)F : (const float4*)Imp;
    ushort* dst = (blockIdx.y == 0) ? Fb : Ib;
    if (i < total4) {
        float4 v = src[i];
        ushort4 o;
        o.x = f2bf(v.x); o.y = f2bf(v.y); o.z = f2bf(v.z); o.w = f2bf(v.w);
        *reinterpret_cast<ushort4*>(dst + 4 * (size_t)i) = o;
    }
}

// ---------------- kernel 0b: label histogram (14 bins) ----------------
__global__ void label_hist(const int* __restrict__ labels, int* __restrict__ counts) {
    __shared__ int c[16];
    if (threadIdx.x < 16) c[threadIdx.x] = 0;
    __syncthreads();
    for (int i = threadIdx.x; i < N; i += blockDim.x) atomicAdd(&c[labels[i]], 1);
    __syncthreads();
    if (threadIdx.x < 16) counts[threadIdx.x] = c[threadIdx.x];
}

// ---------------- kernel 1: single-pass tile kernel ----------------
// Computes exp(masked logits) for each (i,j) ONCE; accumulates row-sums in
// registers and col-sums via shfl + shared LDS atomic accumulator.
// blockIdx.x: row block (128 rows), blockIdx.y: column slice (512 cols).
__launch_bounds__(256, 4)
__global__ void tile_pass(const ushort* __restrict__ Fb, const ushort* __restrict__ Ib,
                          const int* __restrict__ labels,
                          float* __restrict__ partials_row,    // [N][NSLICE]
                          float* __restrict__ partials_col) {  // [NRB][N]
    __shared__ ushort Bsh[2][CB * D];           // 2 x 16KB, fragment-ordered
    __shared__ float colacc[COLS_PER_SLICE];    // 2KB, ds_add_f32 accumulated
    __shared__ int labs[COLS_PER_SLICE];        // 2KB

    const int tid = threadIdx.x;
    const int lane = tid & 63;
    const int wave = tid >> 6;
    const int rb = blockIdx.x;
    const int row0 = rb * BM + wave * 32;       // 2 row-tiles of 16
    const int c0 = blockIdx.y * COLS_PER_SLICE;
    const int lrow = lane & 15;                 // A-row / B-col within tile
    const int kgrp = lane >> 4;                 // 0..3

    // stage a 32-col tile: 16 chunks of 1KB; chunk = u*8+ks; wave w stages 4w..4w+3.
    // chunk layout: lane l's 16B at chunk_base + l*16 = B[cbase+u*16+(l&15)][ks*32+(l>>4)*8 ..+7]
#define STAGE(buf, ct)                                                                  \
    {                                                                                   \
        const int cbase = c0 + (ct) * CB;                                               \
        _Pragma("unroll")                                                               \
        for (int i = 0; i < 4; ++i) {                                                   \
            const int chunk = wave * 4 + i;                                             \
            const int u = chunk >> 3, ks = chunk & 7;                                   \
            const ushort* src =                                                         \
                Ib + (size_t)(cbase + u * 16 + lrow) * D + ks * 32 + kgrp * 8;          \
            gload_lds16(src, &Bsh[buf][chunk * 512]);                                   \
        }                                                                               \
    }

    STAGE(0, 0);

    // init colacc + label cache while loads fly
    for (int i = tid; i < COLS_PER_SLICE; i += 256) {
        labs[i] = labels[c0 + i];
        colacc[i] = 0.0f;
    }

    // A fragments held in registers for the whole block (K=256 fits)
    bf16x8 afrag[2][8];
#pragma unroll
    for (int t = 0; t < 2; ++t) {
        const ushort* arow = Fb + (size_t)(row0 + t * 16 + lrow) * D;
#pragma unroll
        for (int ks = 0; ks < 8; ++ks)
            afrag[t][ks] = *reinterpret_cast<const bf16x8*>(arow + ks * 32 + kgrp * 8);
    }

    int labr[2][4];
#pragma unroll
    for (int t = 0; t < 2; ++t)
#pragma unroll
        for (int r = 0; r < 4; ++r)
            labr[t][r] = labels[row0 + t * 16 + kgrp * 4 + r];

    float s[2][4];
#pragma unroll
    for (int t = 0; t < 2; ++t)
#pragma unroll
        for (int r = 0; r < 4; ++r) s[t][r] = 0.0f;

    asm volatile("s_waitcnt vmcnt(0)" ::: "memory");
    __syncthreads();

    int cur = 0;
    for (int ct = 0; ct < NT; ++ct) {
        if (ct + 1 < NT) STAGE(cur ^ 1, ct + 1);  // prefetch next tile

#pragma unroll
        for (int u = 0; u < 2; ++u) {
            bf16x8 bfrag[8];
#pragma unroll
            for (int ks = 0; ks < 8; ++ks)
                bfrag[ks] = *reinterpret_cast<const bf16x8*>(
                    &Bsh[cur][(u * 8 + ks) * 512 + lane * 8]);  // linear: conflict-free

            const int labc = labs[ct * CB + u * 16 + lrow];
            float colpart = 0.0f;
#pragma unroll
            for (int t = 0; t < 2; ++t) {
                f32x4 acc = {0.f, 0.f, 0.f, 0.f};
#pragma unroll
                for (int ks = 0; ks < 8; ++ks)
                    acc = __builtin_amdgcn_mfma_f32_16x16x32_bf16(afrag[t][ks], bfrag[ks], acc, 0, 0, 0);

                // D layout: col = lane&15, row = (lane>>4)*4 + r
#pragma unroll
                for (int r = 0; r < 4; ++r) {
                    float arg = __builtin_fmaf(acc[r], K2LOG2E, -CSHIFT);
                    arg = (labr[t][r] == labc) ? -1000.0f : arg;  // masked (incl. diag) -> 0
                    float e = fast_exp2(arg);
                    s[t][r] += e;
                    colpart += e;
                }
            }
            // col-sum over this wave's 32 rows, then one LDS atomic per column
            colpart += __shfl_xor(colpart, 16, 64);
            colpart += __shfl_xor(colpart, 32, 64);
            if (kgrp == 0)
                atomicAdd(&colacc[ct * CB + u * 16 + lrow], colpart);
        }

        asm volatile("s_waitcnt vmcnt(0)" ::: "memory");  // next tile landed
        __syncthreads();                                  // + everyone done with cur
        cur ^= 1;
    }

    // row partials: sum the 16 lrow-lanes (disjoint column subsets)
#pragma unroll
    for (int off = 1; off < 16; off <<= 1) {
#pragma unroll
        for (int t = 0; t < 2; ++t)
#pragma unroll
            for (int r = 0; r < 4; ++r)
                s[t][r] += __shfl_xor(s[t][r], off, 64);
    }
    if (lrow == 0) {
#pragma unroll
        for (int t = 0; t < 2; ++t)
#pragma unroll
            for (int r = 0; r < 4; ++r) {
                const int grow = row0 + t * 16 + kgrp * 4 + r;
                partials_row[(size_t)grow * NSLICE + blockIdx.y] = s[t][r];
            }
    }

    __syncthreads();  // colacc atomics done
    for (int i = tid; i < COLS_PER_SLICE; i += 256)
        partials_col[(size_t)rb * N + c0 + i] = colacc[i];
#undef STAGE
}

// ---------------- kernel 1b: reduce col partials over row blocks ----------------
__global__ void col_reduce(const float* __restrict__ partials_col, float* __restrict__ colsum) {
    const int c = blockIdx.x * 256 + threadIdx.x;
    float v = 0.0f;
    for (int rbi = 0; rbi < NRB; ++rbi) v += partials_col[(size_t)rbi * N + c];
    colsum[c] = v;
}

// exact lse over { S*2^CSHIFT (bulk), cnt*exp(0), exp(diag) }
__device__ inline float final_lse(float S, float cntlog, float diag) {
    float l1 = (S > 0.0f) ? (CSHIFT + fast_log2(S)) * LN2F : -INFINITY;
    float M = fmaxf(fmaxf(l1, cntlog), diag);  // M finite: diag always finite
    return M + __logf(__expf(l1 - M) + __expf(cntlog - M) + __expf(diag - M));
}

// ---------------- kernel 2: per-row contribution (wave per row) ----------------
__global__ void row_contrib(const float* __restrict__ F, const float* __restrict__ Imp,
                            const float* __restrict__ partials_row,
                            const float* __restrict__ colsum,
                            const int* __restrict__ counts,
                            const int* __restrict__ labels, float* __restrict__ blockSums) {
    const int lane = threadIdx.x & 63;
    const int wave = threadIdx.x >> 6;
    const int row = blockIdx.x * 4 + wave;

    // fp32 diagonal dot: 256 floats = 64 lanes * float4
    float4 a = reinterpret_cast<const float4*>(F + (size_t)row * D)[lane];
    float4 b = reinterpret_cast<const float4*>(Imp + (size_t)row * D)[lane];
    float dot = a.x * b.x + a.y * b.y + a.z * b.z + a.w * b.w;
#pragma unroll
    for (int off = 32; off > 0; off >>= 1) dot += __shfl_xor(dot, off, 64);

    __shared__ float sums[4];
    if (lane == 0) {
        const float diag = 2.0f * dot;                 // temperature 0.5
        const int cnt = counts[labels[row]] - 1;       // equal-label count excl. self
        const float cntlog = (cnt > 0) ? __logf((float)cnt) : -INFINITY;
        float S_row = 0.0f;
#pragma unroll
        for (int k = 0; k < NSLICE; ++k) S_row += partials_row[(size_t)row * NSLICE + k];
        const float S_col = colsum[row];
        const float lse_total = final_lse(S_row, cntlog, diag) + final_lse(S_col, cntlog, diag);
        sums[wave] = 2.0f * diag - lse_total;
    }
    __syncthreads();
    if (threadIdx.x == 0)
        blockSums[blockIdx.x] = sums[0] + sums[1] + sums[2] + sums[3];
}

// ---------------- kernel 3: final deterministic reduce ----------------
__global__ void final_reduce(const float* __restrict__ blockSums, float* __restrict__ out) {
    __shared__ float red[256];
    float v = 0.0f;
    for (int i = threadIdx.x; i < N / 4; i += 256) v += blockSums[i];
    red[threadIdx.x] = v;
    __syncthreads();
    for (int st = 128; st > 0; st >>= 1) {
        if (threadIdx.x < st) red[threadIdx.x] += red[threadIdx.x + st];
        __syncthreads();
    }
    if (threadIdx.x == 0) out[0] = -red[0] / (float)N;
}

extern "C" void kernel_launch(void* const* d_in, const int* in_sizes, int n_in,
                              void* d_out, int out_size, void* d_ws, size_t ws_size,
                              hipStream_t stream) {
    const float* F = (const float*)d_in[0];
    const float* Imp = (const float*)d_in[1];
    const int* labels = (const int*)d_in[2];
    float* out = (float*)d_out;

    char* ws = (char*)d_ws;
    size_t off = 0;
    ushort* Fb = (ushort*)(ws + off); off += (size_t)N * D * 2;               // 4 MB
    ushort* Ib = (ushort*)(ws + off); off += (size_t)N * D * 2;               // 4 MB
    float* partials_row = (float*)(ws + off); off += (size_t)N * NSLICE * 4;  // 512 KB
    float* partials_col = (float*)(ws + off); off += (size_t)NRB * N * 4;     // 2 MB
    float* colsum = (float*)(ws + off); off += (size_t)N * 4;                 // 32 KB
    float* blockSums = (float*)(ws + off); off += (size_t)(N / 4) * 4;        // 8 KB
    int* counts = (int*)(ws + off);

    dim3 cgrid((N * D / 4 + 255) / 256, 2);
    convert_bf16<<<cgrid, 256, 0, stream>>>(F, Imp, Fb, Ib);
    label_hist<<<1, 256, 0, stream>>>(labels, counts);

    dim3 g(NRB, NSLICE);
    tile_pass<<<g, 256, 0, stream>>>(Fb, Ib, labels, partials_row, partials_col);

    col_reduce<<<N / 256, 256, 0, stream>>>(partials_col, colsum);
    row_contrib<<<N / 4, 256, 0, stream>>>(F, Imp, partials_row, colsum, counts, labels, blockSums);
    final_reduce<<<1, 256, 0, stream>>>(blockSums, out);
}

// Round 6
// 88.512 us; speedup vs baseline: 1.5013x; 1.5013x over previous
//
#include <hip/hip_runtime.h>
#include <hip/hip_bf16.h>

#define N 8192
#define D 256
#define NSLICE 8
#define BM 128                       // rows per block (4 waves x 32 rows)
#define CB 32                        // cols per staged LDS tile
#define COLS_PER_SLICE (N / NSLICE)  // 1024
#define NT (COLS_PER_SLICE / CB)     // 32 tiles per block
#define NRB (N / BM)                 // 64 row blocks
#define TILE_E (CB * D)              // 8192 ushorts = 16 KB per tile

#define CSHIFT 160.0f                // fixed base-2 LSE shift
#define K2LOG2E 2.885390082f         // (1/T) * log2(e) = 2 * 1.44269504
#define LN2F 0.6931471805599453f

typedef __attribute__((ext_vector_type(8))) short bf16x8;
typedef __attribute__((ext_vector_type(4))) float f32x4;

__device__ inline float fast_exp2(float x) { return __builtin_amdgcn_exp2f(x); }
__device__ inline float fast_log2(float x) { return __builtin_amdgcn_logf(x); }

// async global->LDS, 16B per lane; LDS dest = wave-uniform base + lane*16,
// global src is per-lane (carries the fragment layout).
__device__ inline void gload_lds16(const ushort* g, ushort* l) {
    __builtin_amdgcn_global_load_lds(
        (const __attribute__((address_space(1))) void*)g,
        (__attribute__((address_space(3))) void*)l, 16, 0, 0);
}

__device__ inline ushort f2bf(float x) {
    __hip_bfloat16 h = __float2bfloat16(x);
    return *reinterpret_cast<ushort*>(&h);
}

// ---------------- kernel 0: fp32 -> bf16 conversion ----------------
__global__ void convert_bf16(const float* __restrict__ F, const float* __restrict__ Imp,
                             ushort* __restrict__ Fb, ushort* __restrict__ Ib) {
    const int i = blockIdx.x * blockDim.x + threadIdx.x;  // float4 index
    const int total4 = N * D / 4;
    const float4* src = (blockIdx.y == 0) ? (const float4*)F : (const float4*)Imp;
    ushort* dst = (blockIdx.y == 0) ? Fb : Ib;
    if (i < total4) {
        float4 v = src[i];
        ushort4 o;
        o.x = f2bf(v.x); o.y = f2bf(v.y); o.z = f2bf(v.z); o.w = f2bf(v.w);
        *reinterpret_cast<ushort4*>(dst + 4 * (size_t)i) = o;
    }
}

// ---------------- kernel 0b: label histogram (14 bins) ----------------
__global__ void label_hist(const int* __restrict__ labels, int* __restrict__ counts) {
    __shared__ int c[16];
    if (threadIdx.x < 16) c[threadIdx.x] = 0;
    __syncthreads();
    for (int i = threadIdx.x; i < N; i += blockDim.x) atomicAdd(&c[labels[i]], 1);
    __syncthreads();
    if (threadIdx.x < 16) counts[threadIdx.x] = c[threadIdx.x];
}

// ---------------- kernel 1: single-pass tile kernel ----------------
// Computes exp(masked logits) for each (i,j) ONCE; row-sums in registers,
// col-sums in per-wave LDS. Triple-buffered staging, counted vmcnt (T3+T4),
// raw s_barrier (no implicit vmcnt(0) drain), setprio around compute (T5).
// blockIdx.x: row block (128 rows), blockIdx.y: column slice (1024 cols).
__launch_bounds__(256, 2)
__global__ void tile_pass(const ushort* __restrict__ Fb, const ushort* __restrict__ Ib,
                          const int* __restrict__ labels,
                          float* __restrict__ partials_row,    // [N][NSLICE]
                          float* __restrict__ partials_col) {  // [NRB][N]
    __shared__ ushort Bsh[3 * TILE_E];          // 3 x 16KB, fragment-ordered
    __shared__ float colacc[4][COLS_PER_SLICE]; // 16KB, per-wave private rows
    __shared__ int labs[COLS_PER_SLICE];        // 4KB

    const int tid = threadIdx.x;
    const int lane = tid & 63;
    const int wave = tid >> 6;
    const int rb = blockIdx.x;
    const int row0 = rb * BM + wave * 32;       // 2 row-tiles of 16
    const int c0 = blockIdx.y * COLS_PER_SLICE;
    const int lrow = lane & 15;                 // A-row / B-col within tile
    const int kgrp = lane >> 4;                 // 0..3

    // stage a 32-col tile: 16 chunks of 1KB; chunk = u*8+ks; wave w stages 4w..4w+3.
    // chunk layout: lane l's 16B at chunk_base + l*16 = B[cbase+u*16+(l&15)][ks*32+(l>>4)*8 ..+7]
#define STAGE(buf, ct)                                                                  \
    {                                                                                   \
        const int cbase = c0 + (ct) * CB;                                               \
        _Pragma("unroll")                                                               \
        for (int i = 0; i < 4; ++i) {                                                   \
            const int chunk = wave * 4 + i;                                             \
            const int u = chunk >> 3, ks = chunk & 7;                                   \
            const ushort* src =                                                         \
                Ib + (size_t)(cbase + u * 16 + lrow) * D + ks * 32 + kgrp * 8;          \
            gload_lds16(src, &Bsh[(buf) * TILE_E + chunk * 512]);                       \
        }                                                                               \
    }

    STAGE(0, 0);
    STAGE(1, 1);

    // init colacc + label cache while loads fly
    for (int i = tid; i < COLS_PER_SLICE; i += 256) {
        labs[i] = labels[c0 + i];
        colacc[0][i] = 0.f; colacc[1][i] = 0.f; colacc[2][i] = 0.f; colacc[3][i] = 0.f;
    }

    // A fragments held in registers for the whole block (K=256 fits)
    bf16x8 afrag[2][8];
#pragma unroll
    for (int t = 0; t < 2; ++t) {
        const ushort* arow = Fb + (size_t)(row0 + t * 16 + lrow) * D;
#pragma unroll
        for (int ks = 0; ks < 8; ++ks)
            afrag[t][ks] = *reinterpret_cast<const bf16x8*>(arow + ks * 32 + kgrp * 8);
    }

    int labr[2][4];
#pragma unroll
    for (int t = 0; t < 2; ++t)
#pragma unroll
        for (int r = 0; r < 4; ++r)
            labr[t][r] = labels[row0 + t * 16 + kgrp * 4 + r];

    float s[2][4];
#pragma unroll
    for (int t = 0; t < 2; ++t)
#pragma unroll
        for (int r = 0; r < 4; ++r) s[t][r] = 0.0f;

    // tile 0 landed (tile 1 may still fly); LDS writes (labs/colacc) visible
    asm volatile("s_waitcnt vmcnt(4) lgkmcnt(0)" ::: "memory");
    __builtin_amdgcn_s_barrier();

    int cbuf = 0, sbuf = 2;
    for (int ct = 0; ct < NT; ++ct) {
        if (ct + 2 < NT) STAGE(sbuf, ct + 2);  // keep 2 tiles in flight

        __builtin_amdgcn_s_setprio(1);
#pragma unroll
        for (int u = 0; u < 2; ++u) {
            bf16x8 bfrag[8];
#pragma unroll
            for (int ks = 0; ks < 8; ++ks)
                bfrag[ks] = *reinterpret_cast<const bf16x8*>(
                    &Bsh[cbuf * TILE_E + (u * 8 + ks) * 512 + lane * 8]);  // linear: conflict-free

            const int labc = labs[ct * CB + u * 16 + lrow];
            float colpart = 0.0f;
#pragma unroll
            for (int t = 0; t < 2; ++t) {
                f32x4 acc = {0.f, 0.f, 0.f, 0.f};
#pragma unroll
                for (int ks = 0; ks < 8; ++ks)
                    acc = __builtin_amdgcn_mfma_f32_16x16x32_bf16(afrag[t][ks], bfrag[ks], acc, 0, 0, 0);

                // D layout: col = lane&15, row = (lane>>4)*4 + r
#pragma unroll
                for (int r = 0; r < 4; ++r) {
                    float arg = __builtin_fmaf(acc[r], K2LOG2E, -CSHIFT);
                    arg = (labr[t][r] == labc) ? -1000.0f : arg;  // masked (incl. diag) -> 0
                    float e = fast_exp2(arg);
                    s[t][r] += e;
                    colpart += e;
                }
            }
            // col-sum over this wave's 32 rows: reduce across kgrp lane groups
            colpart += __shfl_xor(colpart, 16, 64);
            colpart += __shfl_xor(colpart, 32, 64);
            if (kgrp == 0)
                colacc[wave][ct * CB + u * 16 + lrow] += colpart;
        }
        __builtin_amdgcn_s_setprio(0);

        // counted wait: next tile landed, tile-after stays in flight (T4)
        if (ct + 2 < NT) {
            asm volatile("s_waitcnt vmcnt(4)" ::: "memory");
        } else {
            asm volatile("s_waitcnt vmcnt(0)" ::: "memory");
        }
        __builtin_amdgcn_s_barrier();
        cbuf = (cbuf == 2) ? 0 : cbuf + 1;
        sbuf = (sbuf == 2) ? 0 : sbuf + 1;
    }

    // row partials: sum the 16 lrow-lanes (disjoint column subsets)
#pragma unroll
    for (int off = 1; off < 16; off <<= 1) {
#pragma unroll
        for (int t = 0; t < 2; ++t)
#pragma unroll
            for (int r = 0; r < 4; ++r)
                s[t][r] += __shfl_xor(s[t][r], off, 64);
    }
    if (lrow == 0) {
#pragma unroll
        for (int t = 0; t < 2; ++t)
#pragma unroll
            for (int r = 0; r < 4; ++r) {
                const int grow = row0 + t * 16 + kgrp * 4 + r;
                partials_row[(size_t)grow * NSLICE + blockIdx.y] = s[t][r];
            }
    }

    __syncthreads();  // all colacc writes visible
    for (int i = tid; i < COLS_PER_SLICE; i += 256) {
        float v = colacc[0][i] + colacc[1][i] + colacc[2][i] + colacc[3][i];
        partials_col[(size_t)rb * N + c0 + i] = v;
    }
#undef STAGE
}

// ---------------- kernel 1b: reduce col partials over row blocks ----------------
__global__ void col_reduce(const float* __restrict__ partials_col, float* __restrict__ colsum) {
    const int c = blockIdx.x * 256 + threadIdx.x;
    float v = 0.0f;
    for (int rbi = 0; rbi < NRB; ++rbi) v += partials_col[(size_t)rbi * N + c];
    colsum[c] = v;
}

// exact lse over { S*2^CSHIFT (bulk), cnt*exp(0), exp(diag) }
__device__ inline float final_lse(float S, float cntlog, float diag) {
    float l1 = (S > 0.0f) ? (CSHIFT + fast_log2(S)) * LN2F : -INFINITY;
    float M = fmaxf(fmaxf(l1, cntlog), diag);  // M finite: diag always finite
    return M + __logf(__expf(l1 - M) + __expf(cntlog - M) + __expf(diag - M));
}

// ---------------- kernel 2: per-row contribution (wave per row) ----------------
__global__ void row_contrib(const float* __restrict__ F, const float* __restrict__ Imp,
                            const float* __restrict__ partials_row,
                            const float* __restrict__ colsum,
                            const int* __restrict__ counts,
                            const int* __restrict__ labels, float* __restrict__ blockSums) {
    const int lane = threadIdx.x & 63;
    const int wave = threadIdx.x >> 6;
    const int row = blockIdx.x * 4 + wave;

    // fp32 diagonal dot: 256 floats = 64 lanes * float4
    float4 a = reinterpret_cast<const float4*>(F + (size_t)row * D)[lane];
    float4 b = reinterpret_cast<const float4*>(Imp + (size_t)row * D)[lane];
    float dot = a.x * b.x + a.y * b.y + a.z * b.z + a.w * b.w;
#pragma unroll
    for (int off = 32; off > 0; off >>= 1) dot += __shfl_xor(dot, off, 64);

    __shared__ float sums[4];
    if (lane == 0) {
        const float diag = 2.0f * dot;                 // temperature 0.5
        const int cnt = counts[labels[row]] - 1;       // equal-label count excl. self
        const float cntlog = (cnt > 0) ? __logf((float)cnt) : -INFINITY;
        float S_row = 0.0f;
#pragma unroll
        for (int k = 0; k < NSLICE; ++k) S_row += partials_row[(size_t)row * NSLICE + k];
        const float S_col = colsum[row];
        const float lse_total = final_lse(S_row, cntlog, diag) + final_lse(S_col, cntlog, diag);
        sums[wave] = 2.0f * diag - lse_total;
    }
    __syncthreads();
    if (threadIdx.x == 0)
        blockSums[blockIdx.x] = sums[0] + sums[1] + sums[2] + sums[3];
}

// ---------------- kernel 3: final deterministic reduce ----------------
__global__ void final_reduce(const float* __restrict__ blockSums, float* __restrict__ out) {
    __shared__ float red[256];
    float v = 0.0f;
    for (int i = threadIdx.x; i < N / 4; i += 256) v += blockSums[i];
    red[threadIdx.x] = v;
    __syncthreads();
    for (int st = 128; st > 0; st >>= 1) {
        if (threadIdx.x < st) red[threadIdx.x] += red[threadIdx.x + st];
        __syncthreads();
    }
    if (threadIdx.x == 0) out[0] = -red[0] / (float)N;
}

extern "C" void kernel_launch(void* const* d_in, const int* in_sizes, int n_in,
                              void* d_out, int out_size, void* d_ws, size_t ws_size,
                              hipStream_t stream) {
    const float* F = (const float*)d_in[0];
    const float* Imp = (const float*)d_in[1];
    const int* labels = (const int*)d_in[2];
    float* out = (float*)d_out;

    char* ws = (char*)d_ws;
    size_t off = 0;
    ushort* Fb = (ushort*)(ws + off); off += (size_t)N * D * 2;               // 4 MB
    ushort* Ib = (ushort*)(ws + off); off += (size_t)N * D * 2;               // 4 MB
    float* partials_row = (float*)(ws + off); off += (size_t)N * NSLICE * 4;  // 256 KB
    float* partials_col = (float*)(ws + off); off += (size_t)NRB * N * 4;     // 2 MB
    float* colsum = (float*)(ws + off); off += (size_t)N * 4;                 // 32 KB
    float* blockSums = (float*)(ws + off); off += (size_t)(N / 4) * 4;        // 8 KB
    int* counts = (int*)(ws + off);

    dim3 cgrid((N * D / 4 + 255) / 256, 2);
    convert_bf16<<<cgrid, 256, 0, stream>>>(F, Imp, Fb, Ib);
    label_hist<<<1, 256, 0, stream>>>(labels, counts);

    dim3 g(NRB, NSLICE);
    tile_pass<<<g, 256, 0, stream>>>(Fb, Ib, labels, partials_row, partials_col);

    col_reduce<<<N / 256, 256, 0, stream>>>(partials_col, colsum);
    row_contrib<<<N / 4, 256, 0, stream>>>(F, Imp, partials_row, colsum, counts, labels, blockSums);
    final_reduce<<<1, 256, 0, stream>>>(blockSums, out);
}

// Round 7
// 72.208 us; speedup vs baseline: 1.8403x; 1.2258x over previous
//
#include <hip/hip_runtime.h>
#include <hip/hip_bf16.h>

#define N 8192
#define D 256
#define NSLICE 16
#define BM 256                       // rows per block (4 waves x 64 rows)
#define TROWS 4                      // row-tiles of 16 per wave
#define CB 32                        // cols per staged LDS tile
#define COLS_PER_SLICE (N / NSLICE)  // 512
#define NT (COLS_PER_SLICE / CB)     // 16 tiles per block
#define NRB (N / BM)                 // 32 row blocks
#define TILE_E (CB * D)              // 8192 ushorts = 16 KB per tile

#define CSHIFT 160.0f                // fixed base-2 LSE shift
#define K2LOG2E 2.885390082f         // (1/T) * log2(e) = 2 * 1.44269504
#define LN2F 0.6931471805599453f

typedef __attribute__((ext_vector_type(8))) short bf16x8;
typedef __attribute__((ext_vector_type(4))) float f32x4;

__device__ inline float fast_exp2(float x) { return __builtin_amdgcn_exp2f(x); }
__device__ inline float fast_log2(float x) { return __builtin_amdgcn_logf(x); }

// async global->LDS, 16B per lane; LDS dest = wave-uniform base + lane*16,
// global src is per-lane (carries the fragment layout).
__device__ inline void gload_lds16(const ushort* g, ushort* l) {
    __builtin_amdgcn_global_load_lds(
        (const __attribute__((address_space(1))) void*)g,
        (__attribute__((address_space(3))) void*)l, 16, 0, 0);
}

__device__ inline ushort f2bf(float x) {
    __hip_bfloat16 h = __float2bfloat16(x);
    return *reinterpret_cast<ushort*>(&h);
}

// ---------------- kernel 0: fp32 -> bf16 conversion ----------------
__global__ void convert_bf16(const float* __restrict__ F, const float* __restrict__ Imp,
                             ushort* __restrict__ Fb, ushort* __restrict__ Ib) {
    const int i = blockIdx.x * blockDim.x + threadIdx.x;  // float4 index
    const int total4 = N * D / 4;
    const float4* src = (blockIdx.y == 0) ? (const float4*)F : (const float4*)Imp;
    ushort* dst = (blockIdx.y == 0) ? Fb : Ib;
    if (i < total4) {
        float4 v = src[i];
        ushort4 o;
        o.x = f2bf(v.x); o.y = f2bf(v.y); o.z = f2bf(v.z); o.w = f2bf(v.w);
        *reinterpret_cast<ushort4*>(dst + 4 * (size_t)i) = o;
    }
}

// ---------------- kernel 0b: label histogram (14 bins) ----------------
__global__ void label_hist(const int* __restrict__ labels, int* __restrict__ counts) {
    __shared__ int c[16];
    if (threadIdx.x < 16) c[threadIdx.x] = 0;
    __syncthreads();
    for (int i = threadIdx.x; i < N; i += blockDim.x) atomicAdd(&c[labels[i]], 1);
    __syncthreads();
    if (threadIdx.x < 16) counts[threadIdx.x] = c[threadIdx.x];
}

// ---------------- kernel 1: single-pass tile kernel ----------------
// 64 rows/wave (4 row-tiles in registers): each 8x ds_read_b128 B-fragment
// feeds 32 MFMAs (halves LDS bytes per element vs 32 rows/wave).
// Triple-buffered staging, counted vmcnt, raw s_barrier, setprio.
// blockIdx.x: row block (256 rows), blockIdx.y: column slice (512 cols).
__launch_bounds__(256, 2)
__global__ void tile_pass(const ushort* __restrict__ Fb, const ushort* __restrict__ Ib,
                          const int* __restrict__ labels,
                          float* __restrict__ partials_row,    // [N][NSLICE]
                          float* __restrict__ partials_col) {  // [NRB][N]
    __shared__ ushort Bsh[3 * TILE_E];              // 3 x 16KB, fragment-ordered
    __shared__ float colacc[4][COLS_PER_SLICE];     // 8KB, per-wave private rows
    __shared__ int labs[COLS_PER_SLICE];            // 2KB

    const int tid = threadIdx.x;
    const int lane = tid & 63;
    const int wave = tid >> 6;
    const int rb = blockIdx.x;
    const int row0 = rb * BM + wave * (16 * TROWS); // 4 row-tiles of 16
    const int c0 = blockIdx.y * COLS_PER_SLICE;
    const int lrow = lane & 15;                     // A-row / B-col within tile
    const int kgrp = lane >> 4;                     // 0..3

    // stage a 32-col tile: 16 chunks of 1KB; chunk = u*8+ks; wave w stages 4w..4w+3.
    // chunk layout: lane l's 16B at chunk_base + l*16 = B[cbase+u*16+(l&15)][ks*32+(l>>4)*8 ..+7]
#define STAGE(buf, ct)                                                                  \
    {                                                                                   \
        const int cbase = c0 + (ct) * CB;                                               \
        _Pragma("unroll")                                                               \
        for (int i = 0; i < 4; ++i) {                                                   \
            const int chunk = wave * 4 + i;                                             \
            const int u = chunk >> 3, ks = chunk & 7;                                   \
            const ushort* src =                                                         \
                Ib + (size_t)(cbase + u * 16 + lrow) * D + ks * 32 + kgrp * 8;          \
            gload_lds16(src, &Bsh[(buf) * TILE_E + chunk * 512]);                       \
        }                                                                               \
    }

    STAGE(0, 0);
    STAGE(1, 1);

    // init colacc + label cache while loads fly
    for (int i = tid; i < COLS_PER_SLICE; i += 256) {
        labs[i] = labels[c0 + i];
        colacc[0][i] = 0.f; colacc[1][i] = 0.f; colacc[2][i] = 0.f; colacc[3][i] = 0.f;
    }

    // A fragments held in registers for the whole block (4 tiles x K=256)
    bf16x8 afrag[TROWS][8];
#pragma unroll
    for (int t = 0; t < TROWS; ++t) {
        const ushort* arow = Fb + (size_t)(row0 + t * 16 + lrow) * D;
#pragma unroll
        for (int ks = 0; ks < 8; ++ks)
            afrag[t][ks] = *reinterpret_cast<const bf16x8*>(arow + ks * 32 + kgrp * 8);
    }

    int labr[TROWS][4];
#pragma unroll
    for (int t = 0; t < TROWS; ++t)
#pragma unroll
        for (int r = 0; r < 4; ++r)
            labr[t][r] = labels[row0 + t * 16 + kgrp * 4 + r];

    float s[TROWS][4];
#pragma unroll
    for (int t = 0; t < TROWS; ++t)
#pragma unroll
        for (int r = 0; r < 4; ++r) s[t][r] = 0.0f;

    // tile 0 landed (tile 1 may still fly); LDS writes (labs/colacc) visible
    asm volatile("s_waitcnt vmcnt(4) lgkmcnt(0)" ::: "memory");
    __builtin_amdgcn_s_barrier();

    int cbuf = 0, sbuf = 2;
    for (int ct = 0; ct < NT; ++ct) {
        if (ct + 2 < NT) STAGE(sbuf, ct + 2);  // keep 2 tiles in flight

        __builtin_amdgcn_s_setprio(1);
#pragma unroll
        for (int u = 0; u < 2; ++u) {
            bf16x8 bfrag[8];
#pragma unroll
            for (int ks = 0; ks < 8; ++ks)
                bfrag[ks] = *reinterpret_cast<const bf16x8*>(
                    &Bsh[cbuf * TILE_E + (u * 8 + ks) * 512 + lane * 8]);  // linear: conflict-free

            const int labc = labs[ct * CB + u * 16 + lrow];
            float colpart = 0.0f;
#pragma unroll
            for (int t = 0; t < TROWS; ++t) {
                f32x4 acc = {0.f, 0.f, 0.f, 0.f};
#pragma unroll
                for (int ks = 0; ks < 8; ++ks)
                    acc = __builtin_amdgcn_mfma_f32_16x16x32_bf16(afrag[t][ks], bfrag[ks], acc, 0, 0, 0);

                // D layout: col = lane&15, row = (lane>>4)*4 + r
#pragma unroll
                for (int r = 0; r < 4; ++r) {
                    float arg = __builtin_fmaf(acc[r], K2LOG2E, -CSHIFT);
                    arg = (labr[t][r] == labc) ? -1000.0f : arg;  // masked (incl. diag) -> 0
                    float e = fast_exp2(arg);
                    s[t][r] += e;
                    colpart += e;
                }
            }
            // col-sum over this wave's 64 rows: reduce across kgrp lane groups
            colpart += __shfl_xor(colpart, 16, 64);
            colpart += __shfl_xor(colpart, 32, 64);
            if (kgrp == 0)
                colacc[wave][ct * CB + u * 16 + lrow] += colpart;
        }
        __builtin_amdgcn_s_setprio(0);

        // counted wait: next tile landed, tile-after stays in flight (T4)
        if (ct + 2 < NT) {
            asm volatile("s_waitcnt vmcnt(4)" ::: "memory");
        } else {
            asm volatile("s_waitcnt vmcnt(0)" ::: "memory");
        }
        __builtin_amdgcn_s_barrier();
        cbuf = (cbuf == 2) ? 0 : cbuf + 1;
        sbuf = (sbuf == 2) ? 0 : sbuf + 1;
    }

    // row partials: sum the 16 lrow-lanes (disjoint column subsets)
#pragma unroll
    for (int off = 1; off < 16; off <<= 1) {
#pragma unroll
        for (int t = 0; t < TROWS; ++t)
#pragma unroll
            for (int r = 0; r < 4; ++r)
                s[t][r] += __shfl_xor(s[t][r], off, 64);
    }
    if (lrow == 0) {
#pragma unroll
        for (int t = 0; t < TROWS; ++t)
#pragma unroll
            for (int r = 0; r < 4; ++r) {
                const int grow = row0 + t * 16 + kgrp * 4 + r;
                partials_row[(size_t)grow * NSLICE + blockIdx.y] = s[t][r];
            }
    }

    __syncthreads();  // all colacc writes visible
    for (int i = tid; i < COLS_PER_SLICE; i += 256) {
        float v = colacc[0][i] + colacc[1][i] + colacc[2][i] + colacc[3][i];
        partials_col[(size_t)rb * N + c0 + i] = v;
    }
#undef STAGE
}

// ---------------- kernel 1b: reduce col partials over row blocks ----------------
__global__ void col_reduce(const float* __restrict__ partials_col, float* __restrict__ colsum) {
    const int c = blockIdx.x * 256 + threadIdx.x;
    float v = 0.0f;
    for (int rbi = 0; rbi < NRB; ++rbi) v += partials_col[(size_t)rbi * N + c];
    colsum[c] = v;
}

// exact lse over { S*2^CSHIFT (bulk), cnt*exp(0), exp(diag) }
__device__ inline float final_lse(float S, float cntlog, float diag) {
    float l1 = (S > 0.0f) ? (CSHIFT + fast_log2(S)) * LN2F : -INFINITY;
    float M = fmaxf(fmaxf(l1, cntlog), diag);  // M finite: diag always finite
    return M + __logf(__expf(l1 - M) + __expf(cntlog - M) + __expf(diag - M));
}

// ---------------- kernel 2: per-row contribution (wave per row) ----------------
__global__ void row_contrib(const float* __restrict__ F, const float* __restrict__ Imp,
                            const float* __restrict__ partials_row,
                            const float* __restrict__ colsum,
                            const int* __restrict__ counts,
                            const int* __restrict__ labels, float* __restrict__ blockSums) {
    const int lane = threadIdx.x & 63;
    const int wave = threadIdx.x >> 6;
    const int row = blockIdx.x * 4 + wave;

    // fp32 diagonal dot: 256 floats = 64 lanes * float4
    float4 a = reinterpret_cast<const float4*>(F + (size_t)row * D)[lane];
    float4 b = reinterpret_cast<const float4*>(Imp + (size_t)row * D)[lane];
    float dot = a.x * b.x + a.y * b.y + a.z * b.z + a.w * b.w;
#pragma unroll
    for (int off = 32; off > 0; off >>= 1) dot += __shfl_xor(dot, off, 64);

    __shared__ float sums[4];
    if (lane == 0) {
        const float diag = 2.0f * dot;                 // temperature 0.5
        const int cnt = counts[labels[row]] - 1;       // equal-label count excl. self
        const float cntlog = (cnt > 0) ? __logf((float)cnt) : -INFINITY;
        float S_row = 0.0f;
#pragma unroll
        for (int k = 0; k < NSLICE; ++k) S_row += partials_row[(size_t)row * NSLICE + k];
        const float S_col = colsum[row];
        const float lse_total = final_lse(S_row, cntlog, diag) + final_lse(S_col, cntlog, diag);
        sums[wave] = 2.0f * diag - lse_total;
    }
    __syncthreads();
    if (threadIdx.x == 0)
        blockSums[blockIdx.x] = sums[0] + sums[1] + sums[2] + sums[3];
}

// ---------------- kernel 3: final deterministic reduce ----------------
__global__ void final_reduce(const float* __restrict__ blockSums, float* __restrict__ out) {
    __shared__ float red[256];
    float v = 0.0f;
    for (int i = threadIdx.x; i < N / 4; i += 256) v += blockSums[i];
    red[threadIdx.x] = v;
    __syncthreads();
    for (int st = 128; st > 0; st >>= 1) {
        if (threadIdx.x < st) red[threadIdx.x] += red[threadIdx.x + st];
        __syncthreads();
    }
    if (threadIdx.x == 0) out[0] = -red[0] / (float)N;
}

extern "C" void kernel_launch(void* const* d_in, const int* in_sizes, int n_in,
                              void* d_out, int out_size, void* d_ws, size_t ws_size,
                              hipStream_t stream) {
    const float* F = (const float*)d_in[0];
    const float* Imp = (const float*)d_in[1];
    const int* labels = (const int*)d_in[2];
    float* out = (float*)d_out;

    char* ws = (char*)d_ws;
    size_t off = 0;
    ushort* Fb = (ushort*)(ws + off); off += (size_t)N * D * 2;               // 4 MB
    ushort* Ib = (ushort*)(ws + off); off += (size_t)N * D * 2;               // 4 MB
    float* partials_row = (float*)(ws + off); off += (size_t)N * NSLICE * 4;  // 512 KB
    float* partials_col = (float*)(ws + off); off += (size_t)NRB * N * 4;     // 1 MB
    float* colsum = (float*)(ws + off); off += (size_t)N * 4;                 // 32 KB
    float* blockSums = (float*)(ws + off); off += (size_t)(N / 4) * 4;        // 8 KB
    int* counts = (int*)(ws + off);

    dim3 cgrid((N * D / 4 + 255) / 256, 2);
    convert_bf16<<<cgrid, 256, 0, stream>>>(F, Imp, Fb, Ib);
    label_hist<<<1, 256, 0, stream>>>(labels, counts);

    dim3 g(NRB, NSLICE);
    tile_pass<<<g, 256, 0, stream>>>(Fb, Ib, labels, partials_row, partials_col);

    col_reduce<<<N / 256, 256, 0, stream>>>(partials_col, colsum);
    row_contrib<<<N / 4, 256, 0, stream>>>(F, Imp, partials_row, colsum, counts, labels, blockSums);
    final_reduce<<<1, 256, 0, stream>>>(blockSums, out);
}